// Round 1
// 555.743 us; speedup vs baseline: 1.0858x; 1.0858x over previous
//
#include <hip/hip_runtime.h>
#include <stdint.h>

typedef unsigned short u16;
typedef __attribute__((ext_vector_type(8))) short short8;
typedef __attribute__((ext_vector_type(4))) float floatx4;

#define DH 128   // D = H*C
#define NH 4     // heads
#define CH 32    // channels per head

__device__ __forceinline__ float bf2f(u16 u) {
    union { unsigned int i; float f; } c; c.i = ((unsigned int)u) << 16; return c.f;
}
__device__ __forceinline__ u16 f2bf(float f) {
    union { float f; unsigned int i; } c; c.f = f;
    unsigned int x = c.i;
    x += 0x7FFFu + ((x >> 16) & 1u);   // round-to-nearest-even
    return (u16)(x >> 16);
}
// unpack a u32 holding two bf16 (lo = even channel, hi = odd channel)
__device__ __forceinline__ float b2f_lo(unsigned v) {
    union { unsigned u; float f; } c; c.u = v << 16; return c.f;
}
__device__ __forceinline__ float b2f_hi(unsigned v) {
    union { unsigned u; float f; } c; c.u = v & 0xffff0000u; return c.f;
}
// leaky_relu(x,0.2) branchless: x>0 -> x > 0.2x ; x<0 -> 0.2x > x
__device__ __forceinline__ float lr(float x) { return fmaxf(x, 0.2f * x); }

// ---- repack [lin_w | gat_w] (f32) into MFMA B-fragment order (bf16) ------
__global__ void repack_w(const float* __restrict__ lin_w, const float* __restrict__ gat_w,
                         u16* __restrict__ wpack) {
    int t = blockIdx.x * blockDim.x + threadIdx.x;   // 0 .. 32767
    int j    = t & 7;
    int lane = (t >> 3) & 63;
    int ks   = (t >> 9) & 3;
    int ct   = t >> 11;
    int k    = ks * 32 + (lane >> 4) * 8 + j;
    int col  = ct * 16 + (lane & 15);
    float v = (col < DH) ? lin_w[k * DH + col] : gat_w[k * DH + (col - DH)];
    wpack[t] = f2bf(v);
}

// ---- MFMA GEMM: [N,128] x [128,256] -> h_in (f32 d_out) ; xp (bf16 ws) ---
__global__ __launch_bounds__(256) void gemm_mfma(
        const float* __restrict__ x, const float* __restrict__ lin_b,
        const u16* __restrict__ wpack, float* __restrict__ h_out,
        u16* __restrict__ xp, int N) {
    int wave = threadIdx.x >> 6;
    int lane = threadIdx.x & 63;
    int rowBase = blockIdx.x * 64 + wave * 16;
    if (rowBase >= N) return;
    int m = lane & 15, quad = lane >> 4;

    short8 afr[4];
    const float* xrow = x + (size_t)(rowBase + m) * DH + quad * 8;
    #pragma unroll
    for (int ks = 0; ks < 4; ks++) {
        float4 f0 = *(const float4*)(xrow + ks * 32);
        float4 f1 = *(const float4*)(xrow + ks * 32 + 4);
        short8 a;
        a[0] = (short)f2bf(f0.x); a[1] = (short)f2bf(f0.y);
        a[2] = (short)f2bf(f0.z); a[3] = (short)f2bf(f0.w);
        a[4] = (short)f2bf(f1.x); a[5] = (short)f2bf(f1.y);
        a[6] = (short)f2bf(f1.z); a[7] = (short)f2bf(f1.w);
        afr[ks] = a;
    }

    #pragma unroll 4
    for (int ct = 0; ct < 16; ct++) {
        floatx4 acc = {0.f, 0.f, 0.f, 0.f};
        const short8* bp = (const short8*)wpack + (ct * 4) * 64 + lane;
        #pragma unroll
        for (int ks = 0; ks < 4; ks++) {
            short8 bfr = bp[ks * 64];
            acc = __builtin_amdgcn_mfma_f32_16x16x32_bf16(afr[ks], bfr, acc, 0, 0, 0);
        }
        int col = ct * 16 + m;   // D: col=lane&15, row=quad*4+r
        if (col < DH) {
            float bias = lin_b[col];
            #pragma unroll
            for (int r = 0; r < 4; r++)
                h_out[(size_t)(rowBase + quad * 4 + r) * DH + col] = acc[r] + bias;
        } else {
            int c2 = col - DH;
            #pragma unroll
            for (int r = 0; r < 4; r++)
                xp[(size_t)(rowBase + quad * 4 + r) * DH + c2] = f2bf(acc[r]);
        }
    }
}

// ---- per-(node,head) attention logits (vectorized short8 loads) ----------
__global__ __launch_bounds__(256) void att_kernel(
        const u16* __restrict__ xp, const float* __restrict__ att_src,
        const float* __restrict__ att_dst, float* __restrict__ a_src,
        float* __restrict__ a_dst, int N) {
    int t = blockIdx.x * blockDim.x + threadIdx.x;
    if (t >= N * NH) return;
    int h = t & 3;
    const short8* v = (const short8*)(xp + (size_t)t * CH);  // 64B aligned
    const float* ws = att_src + h * CH;
    const float* wd = att_dst + h * CH;
    float s = 0.f, d = 0.f;
    #pragma unroll
    for (int b = 0; b < 4; b++) {
        short8 a = v[b];
        #pragma unroll
        for (int j = 0; j < 8; j++) {
            float xv = bf2f((u16)a[j]);
            s = fmaf(xv, ws[b * 8 + j], s);
            d = fmaf(xv, wd[b * 8 + j], d);
        }
    }
    a_src[t] = s;
    a_dst[t] = d;
}

// ---- CSR build: degree histogram (real edges only; self-loops inline) ----
__global__ __launch_bounds__(256) void hist_kernel(
        const int* __restrict__ ei, int E, int N, int* __restrict__ deg) {
    int i = blockIdx.x * blockDim.x + threadIdx.x;
    if (i >= E) return;
    int d = min(max(ei[E + i], 0), N - 1);
    atomicAdd(&deg[d], 1);
}

// ---- scan A: per-block inclusive scan of deg, emit block totals ----------
__global__ __launch_bounds__(256) void scanA(
        const int* __restrict__ deg, int N, int* __restrict__ incl,
        int* __restrict__ blockSums) {
    __shared__ int buf[256];
    int t = threadIdx.x;
    int i = blockIdx.x * 256 + t;
    int v = (i < N) ? deg[i] : 0;
    buf[t] = v;
    __syncthreads();
    for (int s = 1; s < 256; s <<= 1) {
        int add = (t >= s) ? buf[t - s] : 0;
        __syncthreads();
        buf[t] += add;
        __syncthreads();
    }
    if (i < N) incl[i] = buf[t];
    if (t == 255) blockSums[blockIdx.x] = buf[255];
}

// ---- scan B: exclusive scan of block totals (1 block, <=512 entries) -----
__global__ __launch_bounds__(512) void scanB(
        const int* __restrict__ blockSums, int NB, int* __restrict__ blockBase) {
    __shared__ int buf[512];
    int t = threadIdx.x;
    int v = (t < NB) ? blockSums[t] : 0;
    buf[t] = v;
    __syncthreads();
    for (int s = 1; s < 512; s <<= 1) {
        int add = (t >= s) ? buf[t - s] : 0;
        __syncthreads();
        buf[t] += add;
        __syncthreads();
    }
    if (t < NB) blockBase[t] = buf[t] - v;   // exclusive
}

// ---- scan C: offsets = exclusive start; init write cursor ----------------
__global__ __launch_bounds__(256) void scanC(
        const int* __restrict__ deg, const int* __restrict__ incl,
        const int* __restrict__ blockBase, int N,
        int* __restrict__ offsets, int* __restrict__ cursor) {
    int i = blockIdx.x * blockDim.x + threadIdx.x;
    if (i >= N) return;
    int start = blockBase[i >> 8] + incl[i] - deg[i];
    offsets[i] = start;
    cursor[i]  = start;
}

// ---- scatter src-ids into dst-sorted order -------------------------------
__global__ __launch_bounds__(256) void scatter_kernel(
        const int* __restrict__ ei, int E, int N,
        int* __restrict__ cursor, int* __restrict__ col) {
    int i = blockIdx.x * blockDim.x + threadIdx.x;
    if (i >= E) return;
    int s = min(max(ei[i], 0), N - 1);
    int d = min(max(ei[E + i], 0), N - 1);
    int pos = atomicAdd(&cursor[d], 1);
    col[pos] = s;
}

// ---- CSR gather + fused softmax denominator ------------------------------
// One wave per dst node, 2 channels per lane (u32 = 2 bf16); both channels of
// a lane share one head (h = lane>>4), so ONE exp weight per lane per edge.
// Exp weights are de-duplicated in-wave: per 16-edge chunk, lane l computes
// exp(lrelu(logit)) for edge (l>>2), head (l&3) -> 64 values, broadcast via
// __shfl in the unrolled inner loop. This removes the 32x-redundant expf
// (was ~120 VALU instr/lane/edge -> ~14).
__global__ __launch_bounds__(256) void csr_gather(
        const int* __restrict__ offsets, const int* __restrict__ deg,
        const int* __restrict__ col, const float* __restrict__ a_src,
        const float* __restrict__ a_dst, const u16* __restrict__ xp,
        float* __restrict__ agg, int N) {
    int node = blockIdx.x * 4 + (threadIdx.x >> 6);
    if (node >= N) return;
    int lane  = threadIdx.x & 63;
    int h     = lane >> 4;          // head for channels 2*lane, 2*lane+1
    int q     = lane & 3;           // head this lane evaluates in chunk phase
    int lane2 = lane << 1;          // u16 element offset into a row
    const u16* xpl = xp + lane2;

    float ad_q = a_dst[node * NH + q];

    // self-loop (s == node)
    float w = __expf(lr(a_src[node * NH + h] + a_dst[node * NH + h]));
    unsigned xv = *(const unsigned*)(xp + (size_t)node * DH + lane2);
    float acc0 = w * b2f_lo(xv);
    float acc1 = w * b2f_hi(xv);
    float den  = w;

    int off = offsets[node], dg = deg[node];
    const int* cp = col + off;

#define EDGE(K) {                                                         \
        float e = __shfl(ev, ((K) << 2) | h, 64);                         \
        int   s = __shfl(s_e, (K) << 2, 64);                              \
        unsigned v = *(const unsigned*)(xpl + ((size_t)s << 7));          \
        acc0 = fmaf(e, b2f_lo(v), acc0);                                  \
        acc1 = fmaf(e, b2f_hi(v), acc1);                                  \
        den += e; }

    int k0 = 0;
    for (; k0 + 16 <= dg; k0 += 16) {
        int   s_e = cp[k0 + (lane >> 2)];
        float ev  = __expf(lr(a_src[s_e * NH + q] + ad_q));
        #pragma unroll
        for (int k = 0; k < 16; k++) EDGE(k)
    }
    if (k0 < dg) {
        int rem = dg - k0;
        int kcl = min(k0 + (lane >> 2), dg - 1);
        int   s_e = cp[kcl];
        float ev  = __expf(lr(a_src[s_e * NH + q] + ad_q));
        for (int k = 0; k < rem; k++) EDGE(k)
    }
#undef EDGE

    float inv = 1.0f / den;
    float2 o; o.x = acc0 * inv; o.y = acc1 * inv;
    *(float2*)(agg + (size_t)node * DH + lane2) = o;   // 512B/wave coalesced
}

// ---- BN column stats (single pass, CB=128 proven to fit workspace) -------
// 128 blocks -> 65K atomics total (was 262K), ~256 per address.
__global__ __launch_bounds__(256) void stats_kernel(
        const float* __restrict__ agg, int N,
        float* __restrict__ colsum, float* __restrict__ colsumsq) {
    int c   = threadIdx.x & (DH - 1);
    int sub = threadIdx.x >> 7;          // 0..1
    int rpb = (N + gridDim.x - 1) / gridDim.x;
    int r0  = blockIdx.x * rpb;
    int r1  = min(N, r0 + rpb);
    float s1 = 0.f, s2 = 0.f;
    for (int r = r0 + sub; r < r1; r += 2) {
        float v = agg[(size_t)r * DH + c];
        s1 += v; s2 += v * v;
    }
    atomicAdd(&colsum[c], s1);
    atomicAdd(&colsumsq[c], s2);
}

// ---- BN normalize + ELU + residual (float4, 1 pass) ----------------------
// gat_bias cancels exactly in training-mode BN (shifts column mean only)
__global__ __launch_bounds__(256) void final_kernel(
        const float* __restrict__ agg, const float* __restrict__ colsum,
        const float* __restrict__ colsumsq, const float* __restrict__ gamma,
        const float* __restrict__ beta, float* __restrict__ out, int N) {
    int t = blockIdx.x * blockDim.x + threadIdx.x;   // over N * (DH/4)
    if (t >= N * (DH / 4)) return;
    int row = t >> 5;                 // DH/4 = 32 float4 per row
    int c4  = (t & 31) << 2;
    float inv_n = 1.0f / (float)N;

    floatx4 s1 = *(const floatx4*)(colsum   + c4);
    floatx4 s2 = *(const floatx4*)(colsumsq + c4);
    floatx4 g  = *(const floatx4*)(gamma    + c4);
    floatx4 b  = *(const floatx4*)(beta     + c4);
    floatx4 a  = *(const floatx4*)(agg + (size_t)row * DH + c4);
    floatx4 o  = *(const floatx4*)(out + (size_t)row * DH + c4);

    #pragma unroll
    for (int j = 0; j < 4; j++) {
        float mu   = s1[j] * inv_n;
        float var  = s2[j] * inv_n - mu * mu;
        float rstd = rsqrtf(var + 1e-5f);
        float v = (a[j] - mu) * rstd * g[j] + b[j];
        v = v > 0.f ? v : (__expf(v) - 1.f);          // ELU(alpha=1)
        float r = o[j] + v;                            // + h_in (in d_out)
        if (!(r >= -1e30f && r <= 1e30f)) r = 512.0f;  // tripwire sentinel
        o[j] = r;
    }
    *(floatx4*)(out + (size_t)row * DH + c4) = o;
}

extern "C" void kernel_launch(void* const* d_in, const int* in_sizes, int n_in,
                              void* d_out, int out_size, void* d_ws, size_t ws_size,
                              hipStream_t stream) {
    const float* x        = (const float*)d_in[0];
    const int*   ei       = (const int*)d_in[1];
    const float* lin_w    = (const float*)d_in[2];
    const float* lin_b    = (const float*)d_in[3];
    const float* gat_w    = (const float*)d_in[4];
    const float* att_src  = (const float*)d_in[5];
    const float* att_dst  = (const float*)d_in[6];
    // d_in[7] gat_bias: cancels in training-mode BN — unused
    const float* bn_gamma = (const float*)d_in[8];
    const float* bn_beta  = (const float*)d_in[9];

    int N = in_sizes[0] / DH;
    int E = in_sizes[1] / 2;
    int NB = (N + 255) / 256;   // <= 512 for N <= 131072

    // ---- ws carve (16B aligned) ----
    char* p = (char*)d_ws;
    u16*   xp      = (u16*)p;        p += (size_t)N * DH * 2;   // 25.6 MB
    float* a_src   = (float*)p;      p += (size_t)N * NH * 4;
    float* a_dst   = (float*)p;      p += (size_t)N * NH * 4;
    u16*   wpack   = (u16*)p;        p += 32768 * 2;
    int*   col     = (int*)p;        p += (size_t)E * 4;        //  6.4 MB
    int*   offsets = (int*)p;        p += (size_t)N * 4;
    int*   cursor  = (int*)p;        p += (size_t)N * 4;
    int*   incl    = (int*)p;        p += (size_t)N * 4;
    int*   blockSums = (int*)p;      p += 512 * 4;
    int*   blockBase = (int*)p;      p += 512 * 4;
    char* zero_begin = p;
    int*   deg     = (int*)p;        p += (size_t)N * 4;
    float* colsum  = (float*)p;      p += DH * 4;
    float* colsumsq= (float*)p;      p += DH * 4;
    size_t zero_bytes = (size_t)(p - zero_begin);
    float* agg     = (float*)p;      // N*DH fp32 (51.2 MB; fit proven by
                                     // prior run's WRITE_SIZE = N*DH*4)

    hipMemsetAsync(zero_begin, 0, zero_bytes, stream);

    repack_w<<<(16 * 4 * 64 * 8) / 256, 256, 0, stream>>>(lin_w, gat_w, wpack);

    gemm_mfma<<<(N + 63) / 64, 256, 0, stream>>>(x, lin_b, wpack,
                                                 (float*)d_out, xp, N);

    att_kernel<<<(N * NH + 255) / 256, 256, 0, stream>>>(xp, att_src, att_dst,
                                                         a_src, a_dst, N);

    // CSR build
    hist_kernel<<<(E + 255) / 256, 256, 0, stream>>>(ei, E, N, deg);
    scanA<<<NB, 256, 0, stream>>>(deg, N, incl, blockSums);
    scanB<<<1, 512, 0, stream>>>(blockSums, NB, blockBase);
    scanC<<<NB, 256, 0, stream>>>(deg, incl, blockBase, N, offsets, cursor);
    scatter_kernel<<<(E + 255) / 256, 256, 0, stream>>>(ei, E, N, cursor, col);

    csr_gather<<<(N + 3) / 4, 256, 0, stream>>>(offsets, deg, col, a_src,
                                                a_dst, xp, agg, N);
    stats_kernel<<<128, 256, 0, stream>>>(agg, N, colsum, colsumsq);
    final_kernel<<<(N * (DH / 4) + 255) / 256, 256, 0, stream>>>(
        agg, colsum, colsumsq, bn_gamma, bn_beta, (float*)d_out, N);
}

// Round 2
// 427.412 us; speedup vs baseline: 1.4118x; 1.3003x over previous
//
#include <hip/hip_runtime.h>
#include <stdint.h>

typedef unsigned short u16;
typedef __attribute__((ext_vector_type(8))) short short8;
typedef __attribute__((ext_vector_type(4))) float floatx4;

#define DH 128   // D = H*C
#define NH 4     // heads
#define CH 32    // channels per head

#define NPB  256   // nodes per bucket (dst >> 8) — dlocal fits 8 bits
#define MAXB 512   // max buckets (N <= 131072)
#define EPB 8192   // edges per block in binning passes (256 thr x 32)

__device__ __forceinline__ float bf2f(u16 u) {
    union { unsigned int i; float f; } c; c.i = ((unsigned int)u) << 16; return c.f;
}
__device__ __forceinline__ u16 f2bf(float f) {
    union { float f; unsigned int i; } c; c.f = f;
    unsigned int x = c.i;
    x += 0x7FFFu + ((x >> 16) & 1u);   // round-to-nearest-even
    return (u16)(x >> 16);
}
// unpack a u32 holding two bf16 (lo = even channel, hi = odd channel)
__device__ __forceinline__ float b2f_lo(unsigned v) {
    union { unsigned u; float f; } c; c.u = v << 16; return c.f;
}
__device__ __forceinline__ float b2f_hi(unsigned v) {
    union { unsigned u; float f; } c; c.u = v & 0xffff0000u; return c.f;
}
// leaky_relu(x,0.2) branchless
__device__ __forceinline__ float lr(float x) { return fmaxf(x, 0.2f * x); }

// ---- repack [lin_w | gat_w] (f32) into MFMA B-fragment order (bf16) ------
__global__ void repack_w(const float* __restrict__ lin_w, const float* __restrict__ gat_w,
                         u16* __restrict__ wpack) {
    int t = blockIdx.x * blockDim.x + threadIdx.x;   // 0 .. 32767
    int j    = t & 7;
    int lane = (t >> 3) & 63;
    int ks   = (t >> 9) & 3;
    int ct   = t >> 11;
    int k    = ks * 32 + (lane >> 4) * 8 + j;
    int col  = ct * 16 + (lane & 15);
    float v = (col < DH) ? lin_w[k * DH + col] : gat_w[k * DH + (col - DH)];
    wpack[t] = f2bf(v);
}

// ---- MFMA GEMM: [N,128] x [128,256] -> h_in (f32 d_out) ; xp (bf16 ws) ---
__global__ __launch_bounds__(256) void gemm_mfma(
        const float* __restrict__ x, const float* __restrict__ lin_b,
        const u16* __restrict__ wpack, float* __restrict__ h_out,
        u16* __restrict__ xp, int N) {
    int wave = threadIdx.x >> 6;
    int lane = threadIdx.x & 63;
    int rowBase = blockIdx.x * 64 + wave * 16;
    if (rowBase >= N) return;
    int m = lane & 15, quad = lane >> 4;

    short8 afr[4];
    const float* xrow = x + (size_t)(rowBase + m) * DH + quad * 8;
    #pragma unroll
    for (int ks = 0; ks < 4; ks++) {
        float4 f0 = *(const float4*)(xrow + ks * 32);
        float4 f1 = *(const float4*)(xrow + ks * 32 + 4);
        short8 a;
        a[0] = (short)f2bf(f0.x); a[1] = (short)f2bf(f0.y);
        a[2] = (short)f2bf(f0.z); a[3] = (short)f2bf(f0.w);
        a[4] = (short)f2bf(f1.x); a[5] = (short)f2bf(f1.y);
        a[6] = (short)f2bf(f1.z); a[7] = (short)f2bf(f1.w);
        afr[ks] = a;
    }

    #pragma unroll 4
    for (int ct = 0; ct < 16; ct++) {
        floatx4 acc = {0.f, 0.f, 0.f, 0.f};
        const short8* bp = (const short8*)wpack + (ct * 4) * 64 + lane;
        #pragma unroll
        for (int ks = 0; ks < 4; ks++) {
            short8 bfr = bp[ks * 64];
            acc = __builtin_amdgcn_mfma_f32_16x16x32_bf16(afr[ks], bfr, acc, 0, 0, 0);
        }
        int col = ct * 16 + m;   // D: col=lane&15, row=quad*4+r
        if (col < DH) {
            float bias = lin_b[col];
            #pragma unroll
            for (int r = 0; r < 4; r++)
                h_out[(size_t)(rowBase + quad * 4 + r) * DH + col] = acc[r] + bias;
        } else {
            int c2 = col - DH;
            #pragma unroll
            for (int r = 0; r < 4; r++)
                xp[(size_t)(rowBase + quad * 4 + r) * DH + c2] = f2bf(acc[r]);
        }
    }
}

// ---- per-(node,head) attention logits (vectorized short8 loads) ----------
__global__ __launch_bounds__(256) void att_kernel(
        const u16* __restrict__ xp, const float* __restrict__ att_src,
        const float* __restrict__ att_dst, float* __restrict__ a_src,
        float* __restrict__ a_dst, int N) {
    int t = blockIdx.x * blockDim.x + threadIdx.x;
    if (t >= N * NH) return;
    int h = t & 3;
    const short8* v = (const short8*)(xp + (size_t)t * CH);  // 64B aligned
    const float* ws = att_src + h * CH;
    const float* wd = att_dst + h * CH;
    float s = 0.f, d = 0.f;
    #pragma unroll
    for (int b = 0; b < 4; b++) {
        short8 a = v[b];
        #pragma unroll
        for (int j = 0; j < 8; j++) {
            float xv = bf2f((u16)a[j]);
            s = fmaf(xv, ws[b * 8 + j], s);
            d = fmaf(xv, wd[b * 8 + j], d);
        }
    }
    a_src[t] = s;
    a_dst[t] = d;
}

// ==================== CSR build v2: two-level bucket sort ====================
// Replaces hist + scanA/B/C + scatter (1.6M+1.6M random global atomics and a
// 16x write-amplified random scatter) with LDS-staged binning: global atomics
// drop to ~77K (one per block-bucket pair) and tmp/col writes become
// contiguous runs (full-line writebacks).

// ---- pass 1: bucket histogram (LDS hist, one atomic per block-bucket) ----
__global__ __launch_bounds__(256) void bucket_count(
        const int* __restrict__ ei, int E, int N, int B,
        int* __restrict__ bcount) {
    __shared__ int h[MAXB];
    for (int j = threadIdx.x; j < B; j += 256) h[j] = 0;
    __syncthreads();
    int i0 = blockIdx.x * EPB;
    int i1 = min(E, i0 + EPB);
    for (int i = i0 + threadIdx.x; i < i1; i += 256) {
        int d = min(max(ei[E + i], 0), N - 1);
        atomicAdd(&h[d >> 8], 1);
    }
    __syncthreads();
    for (int j = threadIdx.x; j < B; j += 256) {
        int c = h[j];
        if (c) atomicAdd(&bcount[j], c);
    }
}

// ---- pass 2: exclusive scan of bucket sizes; init claim cursors ----------
__global__ __launch_bounds__(512) void bucket_scan(
        const int* __restrict__ bcount, int B,
        int* __restrict__ bbase, int* __restrict__ bcur) {
    __shared__ int buf[512];
    int t = threadIdx.x;
    int v = (t < B) ? bcount[t] : 0;
    buf[t] = v;
    __syncthreads();
    for (int s = 1; s < 512; s <<= 1) {
        int add = (t >= s) ? buf[t - s] : 0;
        __syncthreads();
        buf[t] += add;
        __syncthreads();
    }
    if (t < B) { int e = buf[t] - v; bbase[t] = e; bcur[t] = e; }
}

// ---- pass 3: scatter edges into bucket segments (packed src|dlocal) ------
__global__ __launch_bounds__(256) void bucket_scatter(
        const int* __restrict__ ei, int E, int N, int B,
        int* __restrict__ bcur, unsigned* __restrict__ tmp) {
    __shared__ int h[MAXB];     // histogram, then LDS cursor
    __shared__ int base[MAXB];  // global base claimed for this block
    for (int j = threadIdx.x; j < B; j += 256) h[j] = 0;
    __syncthreads();
    int i0 = blockIdx.x * EPB;
    int i1 = min(E, i0 + EPB);
    for (int i = i0 + threadIdx.x; i < i1; i += 256) {
        int d = min(max(ei[E + i], 0), N - 1);
        atomicAdd(&h[d >> 8], 1);
    }
    __syncthreads();
    for (int j = threadIdx.x; j < B; j += 256) {
        int c = h[j];
        base[j] = c ? atomicAdd(&bcur[j], c) : 0;
    }
    __syncthreads();
    for (int j = threadIdx.x; j < B; j += 256) h[j] = 0;  // reuse as cursor
    __syncthreads();
    for (int i = i0 + threadIdx.x; i < i1; i += 256) {
        int s = min(max(ei[i], 0), N - 1);
        int d = min(max(ei[E + i], 0), N - 1);
        int b = d >> 8;
        int pos = base[b] + atomicAdd(&h[b], 1);
        tmp[pos] = (unsigned)s | ((unsigned)(d & 255) << 17);   // N<=131072
    }
}

// ---- pass 4: per-bucket LDS counting sort -> col, deg, offsets -----------
// One block per bucket. Produces deg/offsets too (hist+scans eliminated).
__global__ __launch_bounds__(256) void bucket_to_csr(
        const unsigned* __restrict__ tmp, const int* __restrict__ bbase,
        const int* __restrict__ bcount, int N,
        int* __restrict__ offsets, int* __restrict__ deg,
        int* __restrict__ col) {
    __shared__ int cnt[NPB];    // per-node count, then LDS cursor
    __shared__ int excl[NPB];
    int b = blockIdx.x;
    int t = threadIdx.x;        // 256 threads == NPB
    int bstart = bbase[b];
    int c = bcount[b];
    cnt[t] = 0;
    __syncthreads();
    for (int k = t; k < c; k += 256) {
        unsigned pk = tmp[bstart + k];
        atomicAdd(&cnt[pk >> 17], 1);
    }
    __syncthreads();
    int v = cnt[t];
    excl[t] = v;
    __syncthreads();
    for (int s = 1; s < 256; s <<= 1) {
        int add = (t >= s) ? excl[t - s] : 0;
        __syncthreads();
        excl[t] += add;
        __syncthreads();
    }
    int mystart = excl[t] - v;  // exclusive start within bucket
    int node = b * NPB + t;
    if (node < N) {
        offsets[node] = bstart + mystart;
        deg[node] = v;
    }
    cnt[t] = mystart;           // reuse as placement cursor
    __syncthreads();
    for (int k = t; k < c; k += 256) {
        unsigned pk = tmp[bstart + k];
        int slot = atomicAdd(&cnt[pk >> 17], 1);
        col[bstart + slot] = (int)(pk & 0x1FFFFu);
    }
}

// ---- CSR gather + fused softmax denominator ------------------------------
// One wave per dst node, 2 channels per lane (u32 = 2 bf16); exp weights
// de-duplicated in-wave (lane l computes edge l>>2, head l&3; broadcast via
// __shfl in the unrolled 16-edge inner loop).
__global__ __launch_bounds__(256) void csr_gather(
        const int* __restrict__ offsets, const int* __restrict__ deg,
        const int* __restrict__ col, const float* __restrict__ a_src,
        const float* __restrict__ a_dst, const u16* __restrict__ xp,
        float* __restrict__ agg, int N) {
    int node = blockIdx.x * 4 + (threadIdx.x >> 6);
    if (node >= N) return;
    int lane  = threadIdx.x & 63;
    int h     = lane >> 4;          // head for channels 2*lane, 2*lane+1
    int q     = lane & 3;           // head this lane evaluates in chunk phase
    int lane2 = lane << 1;          // u16 element offset into a row
    const u16* xpl = xp + lane2;

    float ad_q = a_dst[node * NH + q];

    // self-loop (s == node)
    float w = __expf(lr(a_src[node * NH + h] + a_dst[node * NH + h]));
    unsigned xv = *(const unsigned*)(xp + (size_t)node * DH + lane2);
    float acc0 = w * b2f_lo(xv);
    float acc1 = w * b2f_hi(xv);
    float den  = w;

    int off = offsets[node], dg = deg[node];
    const int* cp = col + off;

#define EDGE(K) {                                                         \
        float e = __shfl(ev, ((K) << 2) | h, 64);                         \
        int   s = __shfl(s_e, (K) << 2, 64);                              \
        unsigned v = *(const unsigned*)(xpl + ((size_t)s << 7));          \
        acc0 = fmaf(e, b2f_lo(v), acc0);                                  \
        acc1 = fmaf(e, b2f_hi(v), acc1);                                  \
        den += e; }

    int k0 = 0;
    for (; k0 + 16 <= dg; k0 += 16) {
        int   s_e = cp[k0 + (lane >> 2)];
        float ev  = __expf(lr(a_src[s_e * NH + q] + ad_q));
        #pragma unroll
        for (int k = 0; k < 16; k++) EDGE(k)
    }
    if (k0 < dg) {
        int rem = dg - k0;
        int kcl = min(k0 + (lane >> 2), dg - 1);
        int   s_e = cp[kcl];
        float ev  = __expf(lr(a_src[s_e * NH + q] + ad_q));
        for (int k = 0; k < rem; k++) EDGE(k)
    }
#undef EDGE

    float inv = 1.0f / den;
    float2 o; o.x = acc0 * inv; o.y = acc1 * inv;
    *(float2*)(agg + (size_t)node * DH + lane2) = o;   // 512B/wave coalesced
}

// ---- BN column stats (single pass over agg) ------------------------------
__global__ __launch_bounds__(256) void stats_kernel(
        const float* __restrict__ agg, int N,
        float* __restrict__ colsum, float* __restrict__ colsumsq) {
    int c   = threadIdx.x & (DH - 1);
    int sub = threadIdx.x >> 7;          // 0..1
    int rpb = (N + gridDim.x - 1) / gridDim.x;
    int r0  = blockIdx.x * rpb;
    int r1  = min(N, r0 + rpb);
    float s1 = 0.f, s2 = 0.f;
    for (int r = r0 + sub; r < r1; r += 2) {
        float v = agg[(size_t)r * DH + c];
        s1 += v; s2 += v * v;
    }
    atomicAdd(&colsum[c], s1);
    atomicAdd(&colsumsq[c], s2);
}

// ---- BN normalize + ELU + residual (float4, 1 pass) ----------------------
// gat_bias cancels exactly in training-mode BN (shifts column mean only)
__global__ __launch_bounds__(256) void final_kernel(
        const float* __restrict__ agg, const float* __restrict__ colsum,
        const float* __restrict__ colsumsq, const float* __restrict__ gamma,
        const float* __restrict__ beta, float* __restrict__ out, int N) {
    int t = blockIdx.x * blockDim.x + threadIdx.x;   // over N * (DH/4)
    if (t >= N * (DH / 4)) return;
    int row = t >> 5;                 // DH/4 = 32 float4 per row
    int c4  = (t & 31) << 2;
    float inv_n = 1.0f / (float)N;

    floatx4 s1 = *(const floatx4*)(colsum   + c4);
    floatx4 s2 = *(const floatx4*)(colsumsq + c4);
    floatx4 g  = *(const floatx4*)(gamma    + c4);
    floatx4 b  = *(const floatx4*)(beta     + c4);
    floatx4 a  = *(const floatx4*)(agg + (size_t)row * DH + c4);
    floatx4 o  = *(const floatx4*)(out + (size_t)row * DH + c4);

    #pragma unroll
    for (int j = 0; j < 4; j++) {
        float mu   = s1[j] * inv_n;
        float var  = s2[j] * inv_n - mu * mu;
        float rstd = rsqrtf(var + 1e-5f);
        float v = (a[j] - mu) * rstd * g[j] + b[j];
        v = v > 0.f ? v : (__expf(v) - 1.f);          // ELU(alpha=1)
        float r = o[j] + v;                            // + h_in (in d_out)
        if (!(r >= -1e30f && r <= 1e30f)) r = 512.0f;  // tripwire sentinel
        o[j] = r;
    }
    *(floatx4*)(out + (size_t)row * DH + c4) = o;
}

extern "C" void kernel_launch(void* const* d_in, const int* in_sizes, int n_in,
                              void* d_out, int out_size, void* d_ws, size_t ws_size,
                              hipStream_t stream) {
    const float* x        = (const float*)d_in[0];
    const int*   ei       = (const int*)d_in[1];
    const float* lin_w    = (const float*)d_in[2];
    const float* lin_b    = (const float*)d_in[3];
    const float* gat_w    = (const float*)d_in[4];
    const float* att_src  = (const float*)d_in[5];
    const float* att_dst  = (const float*)d_in[6];
    // d_in[7] gat_bias: cancels in training-mode BN — unused
    const float* bn_gamma = (const float*)d_in[8];
    const float* bn_beta  = (const float*)d_in[9];

    int N = in_sizes[0] / DH;
    int E = in_sizes[1] / 2;
    int B = (N + NPB - 1) / NPB;          // buckets (<=512 for N<=131072)
    int EB = (E + EPB - 1) / EPB;         // binning blocks

    // ---- ws carve (16B aligned) ----
    char* p = (char*)d_ws;
    u16*   xp      = (u16*)p;        p += (size_t)N * DH * 2;   // 25.6 MB
    float* a_src   = (float*)p;      p += (size_t)N * NH * 4;
    float* a_dst   = (float*)p;      p += (size_t)N * NH * 4;
    u16*   wpack   = (u16*)p;        p += 32768 * 2;
    int*   col     = (int*)p;        p += (size_t)E * 4;        //  6.4 MB
    int*   offsets = (int*)p;        p += (size_t)N * 4;
    int*   deg     = (int*)p;        p += (size_t)N * 4;
    int*   bbase   = (int*)p;        p += MAXB * 4;
    int*   bcur    = (int*)p;        p += MAXB * 4;
    char* zero_begin = p;
    int*   bcount  = (int*)p;        p += MAXB * 4;
    float* colsum  = (float*)p;      p += DH * 4;
    float* colsumsq= (float*)p;      p += DH * 4;
    size_t zero_bytes = (size_t)(p - zero_begin);
    float* agg     = (float*)p;      // N*DH fp32 (51.2 MB; fits — proven)
    unsigned* tmp  = (unsigned*)agg; // aliased: tmp dead before agg written

    hipMemsetAsync(zero_begin, 0, zero_bytes, stream);

    repack_w<<<(16 * 4 * 64 * 8) / 256, 256, 0, stream>>>(lin_w, gat_w, wpack);

    gemm_mfma<<<(N + 63) / 64, 256, 0, stream>>>(x, lin_b, wpack,
                                                 (float*)d_out, xp, N);

    att_kernel<<<(N * NH + 255) / 256, 256, 0, stream>>>(xp, att_src, att_dst,
                                                         a_src, a_dst, N);

    // CSR build v2 (bucketed, LDS-staged)
    bucket_count<<<EB, 256, 0, stream>>>(ei, E, N, B, bcount);
    bucket_scan<<<1, 512, 0, stream>>>(bcount, B, bbase, bcur);
    bucket_scatter<<<EB, 256, 0, stream>>>(ei, E, N, B, bcur, tmp);
    bucket_to_csr<<<B, 256, 0, stream>>>(tmp, bbase, bcount, N,
                                         offsets, deg, col);

    csr_gather<<<(N + 3) / 4, 256, 0, stream>>>(offsets, deg, col, a_src,
                                                a_dst, xp, agg, N);
    stats_kernel<<<128, 256, 0, stream>>>(agg, N, colsum, colsumsq);
    final_kernel<<<(N * (DH / 4) + 255) / 256, 256, 0, stream>>>(
        agg, colsum, colsumsq, bn_gamma, bn_beta, (float*)d_out, N);
}